// Round 15
// baseline (1149.999 us; speedup 1.0000x reference)
//
#include <hip/hip_runtime.h>
#include <math.h>

#define NPTS 4096
#define DIM  32
#define MAXSLOTS 50
#define NTHREADS 256
#define ITHREADS 512
#define NELEM 131072      // 4096*32

// ws layout in floats
#define WS_N2X   0
#define WS_N2Y   4096
#define WS_PMIN  8192
#define WS_PMAX  10240
#define WS_EPS   12288
#define WS_MODE  12352    // int modes; [62] = niter
#define WS_FBUF  12416    // f buffer, 2 parity x 4 matrices x 4096 = 32768 floats
#define WS_P     45184    // partials: 2 par x 4 m x 2 half x 4096 float2 = 131072 floats
#define WS_BF    176256   // fp16 pack area: 2*131072 ushorts = 512 KB

// modes
#define M_SKIP   0
#define M_INIT   1
#define M_AVG    2
#define M_ASSIGN 3

typedef short    short8 __attribute__((ext_vector_type(8)));
typedef _Float16 half8  __attribute__((ext_vector_type(8)));
typedef float    f32x4  __attribute__((ext_vector_type(4)));

__device__ __forceinline__ float exp2fast(float a){
#if __has_builtin(__builtin_amdgcn_exp2f)
    return __builtin_amdgcn_exp2f(a);
#else
    return exp2f(a);
#endif
}
__device__ __forceinline__ float log2fast(float a){
#if __has_builtin(__builtin_amdgcn_logf)
    return __builtin_amdgcn_logf(a);
#else
    return log2f(a);
#endif
}

__device__ __forceinline__ short8 pack8(const float* src){
    float4 v0 = ((const float4*)src)[0];
    float4 v1 = ((const float4*)src)[1];
    float vs[8] = {v0.x, v0.y, v0.z, v0.w, v1.x, v1.y, v1.z, v1.w};
    short hv[8];
#pragma unroll
    for (int i = 0; i < 8; i++) {
        union { _Float16 f; short s; } u;
        u.f = (_Float16)vs[i];              // RNE f32->f16
        hv[i] = u.s;
    }
    short8 r = {hv[0],hv[1],hv[2],hv[3],hv[4],hv[5],hv[6],hv[7]};
    return r;
}

// ---------------- fused setup: fp16 pack (x AND y) + norms + minmax partials
__global__ void sink_setup(const float* __restrict__ x, const float* __restrict__ y,
                           float* __restrict__ ws, unsigned short* __restrict__ bf)
{
    __shared__ float2 mm[8][32];
    const int t = threadIdx.x;
    const int b = blockIdx.x;
    const int gtid = b * 256 + t;          // 0..16383

    {
        int e = gtid * 8;
        *(short8*)((short*)bf + e)         = pack8(x + e);
        *(short8*)((short*)bf + NELEM + e) = pack8(y + e);
    }
    if (gtid < 2 * NPTS) {
        const float* src = (gtid < NPTS) ? (x + (size_t)gtid * DIM)
                                         : (y + (size_t)(gtid - NPTS) * DIM);
        const float4* s4 = (const float4*)src;
        float acc = 0.f;
#pragma unroll
        for (int q = 0; q < 8; q++) {
            float4 v = s4[q];
            acc += v.x*v.x + v.y*v.y + v.z*v.z + v.w*v.w;
        }
        ws[gtid] = 0.5f * acc;
    }
    {
        int d = t & 31, rg = t >> 5;
        float mn = 3.4e38f, mx = -3.4e38f;
#pragma unroll
        for (int k = 0; k < 16; k++) {
            int row = b * 128 + k * 8 + rg;
            const float* src = (row < NPTS) ? (x + (size_t)row * DIM)
                                            : (y + (size_t)(row - NPTS) * DIM);
            float v = src[d];
            mn = fminf(mn, v); mx = fmaxf(mx, v);
        }
        mm[rg][d] = make_float2(mn, mx);
    }
    __syncthreads();
    if (t < 32) {
        float2 a = mm[0][t];
#pragma unroll
        for (int g = 1; g < 8; g++) {
            float2 p = mm[g][t];
            a.x = fminf(a.x, p.x); a.y = fmaxf(a.y, p.y);
        }
        ws[WS_PMIN + b * 32 + t] = a.x;
        ws[WS_PMAX + b * 32 + t] = a.y;
    }
}

// ---------------- schedule: diameter -> eps list + mode per slot (+niter)
__global__ void sink_sched(float* __restrict__ ws)
{
    __shared__ float mins[32], maxs[32];
    int t = threadIdx.x;
    if (t < 32) {
        float mn = 3.4e38f, mx = -3.4e38f;
        for (int b = 0; b < 64; b++) {
            mn = fminf(mn, ws[WS_PMIN + b * 32 + t]);
            mx = fmaxf(mx, ws[WS_PMAX + b * 32 + t]);
        }
        mins[t] = mn; maxs[t] = mx;
    }
    __syncthreads();
    if (t == 0) {
        float dia2 = 0.f;
        for (int d = 0; d < 32; d++) {
            float df = maxs[d] - mins[d];
            dia2 += df * df;
        }
        float dia = sqrtf(dia2);
        float* eps = ws + WS_EPS;
        int*  mode = (int*)(ws + WS_MODE);
        double ld    = log((double)dia);
        double start = 2.0 * ld;
        double stop  = 2.0 * log(0.5);
        double step  = 2.0 * log(0.9);
        int K = (int)ceil((stop - start) / step);
        if (K < 0) K = 0;
        if (K > MAXSLOTS - 4) K = MAXSLOTS - 4;
        eps[0] = dia * dia; mode[0] = M_INIT;
        eps[1] = dia * dia; mode[1] = M_AVG;
        for (int k = 0; k < K; k++) {
            eps[2 + k] = (float)exp(start + step * (double)k);
            mode[2 + k] = M_AVG;
        }
        eps[2 + K] = 0.25f; mode[2 + K] = M_AVG;
        eps[3 + K] = 0.25f; mode[3 + K] = M_ASSIGN;
        for (int s = 4 + K; s < MAXSLOTS; s++) { eps[s] = 0.25f; mode[s] = M_SKIP; }
        mode[62] = K + 4;                   // niter
    }
}

// grouped online-LSE over 2 accumulated cts, tile T register R
#define GLSE2(T, R) \
    { float v0 = fmaf(ca##T[0][R], ie2, hpc0); \
      float v1 = fmaf(ca##T[1][R], ie2, hpc1); \
      float nm = fmaxf(fmaxf(v0, v1), ms##T[R]); \
      float er = exp2fast(ms##T[R] - nm); \
      float e0 = exp2fast(v0 - nm); \
      float e1 = exp2fast(v1 - nm); \
      ss##T[R] = fmaf(ss##T[R], er, e0 + e1); \
      ms##T[R] = nm; }

// ---------------- fused softmin iteration: column-split partials
// grid = 4 matrices * 128 row-tiles(32) * 2 col-halves = 1024 blocks, 512 threads
// -> 4 blocks/CU = 8 waves/SIMD, with R8's per-lane B traffic (128 MB/iter).
// Block emits partial (m,s) per row over its 2048-col half; next iteration's
// hp-build merges the two halves to reconstruct the dual (and a designated
// block materializes f into the parity-buffered fbuf).
__global__ __launch_bounds__(ITHREADS, 8) void sink_iter(float* __restrict__ ws, int slot)
{
    const int t = threadIdx.x;
    const int* modes = (const int*)(ws + WS_MODE);
    const int mode = modes[slot];
    if (mode == M_SKIP) return;

    const float eps     = ws[WS_EPS + slot];
    const float inv_eps = 1.0f / eps;
    const float L2E     = 1.4426950408889634f;
    const float ie2     = inv_eps * L2E;
    const float LN2     = 0.6931471805599453f;
    const float hbase   = -8.317766166719343f;   // -ln(4096)

    const int bm   = blockIdx.x >> 8;            // 0=xy 1=yx 2=xx 3=yy
    const int tile = (blockIdx.x >> 1) & 127;    // 32-row tile
    const int h    = blockIdx.x & 1;             // column half
    const int S    = (blockIdx.x * 5) & 15;      // sweep skew over 16 windows
    const int rowIsX = (bm == 0 || bm == 2);
    const int colIsX = (bm == 1 || bm == 2);

    const short* bf = (const short*)(ws + WS_BF);
    const short* rbase = bf + (rowIsX ? 0 : NELEM);
    const short* cbase = bf + (colIsX ? 0 : NELEM);
    const float* cn2 = ws + (colIsX ? WS_N2X : WS_N2Y);
    const int dualsel = (bm == 0) ? 1 : (bm == 1) ? 0 : bm;   // {1,0,2,3}

    __shared__ float  hps[2048];           // 8 KB (this block's column half)
    __shared__ float2 parts[8][32];        // 2 KB

    // ---- hp build: merge prev-slot partials -> dual f -> hp, for our 2048 cols
    if (slot == 0) {
#pragma unroll
        for (int q = 0; q < 4; q++) {
            int jl = t + q * ITHREADS;
            int j  = (h << 11) + jl;
            hps[jl] = (hbase - cn2[j] * inv_eps) * L2E;
        }
    } else {
        const float eps_p  = ws[WS_EPS + slot - 1];
        const int   mode_p = modes[slot - 1];
        const int   pp     = (slot - 1) & 1;
        const float2* P0 = (const float2*)(ws + WS_P) + ((pp * 4 + dualsel) * 2 + 0) * NPTS;
        const float2* P1 = (const float2*)(ws + WS_P) + ((pp * 4 + dualsel) * 2 + 1) * NPTS;
        const float* fr = ws + WS_FBUF + ((slot + 1) & 1) * 16384 + dualsel * NPTS;
        float*       fw = ws + WS_FBUF + (slot & 1) * 16384 + dualsel * NPTS;
        // row-norms of dualsel's rows == cn2 of bm (dual points are our columns)
#pragma unroll
        for (int q = 0; q < 4; q++) {
            int jl = t + q * ITHREADS;
            int j  = (h << 11) + jl;
            float2 p0 = P0[j], p1 = P1[j];
            float mm2 = fmaxf(p0.x, p1.x);
            float sv  = p0.y * exp2fast(p0.x - mm2) + p1.y * exp2fast(p1.x - mm2);
            float lse = LN2 * (mm2 + log2fast(sv));
            float ft  = cn2[j] - eps_p * lse;
            float fv  = (mode_p == M_AVG) ? 0.5f * (fr[j] + ft) : ft;
            if (tile == ((j >> 4) & 127)) fw[j] = fv;   // unique writer per j
            hps[jl] = (hbase + (fv - cn2[j]) * inv_eps) * L2E;
        }
    }
    __syncthreads();

    const int lane = t & 63;
    const int wv   = t >> 6;
    const int lr   = lane & 15;
    const int lk   = (lane >> 4) * 8;

    // A fragments: two row-tiles
    const int ar0 = tile * 32 + lr;
    const half8 a0 = *(const half8*)(rbase + ar0 * DIM + lk);
    const half8 a1 = *(const half8*)(rbase + (ar0 + 16) * DIM + lk);

    // wave's 256-col window within the half: 16 cts; ring-2
    const short* cwb = cbase + (size_t)((h << 11) + wv * 256) * DIM;
    const int laneoff = lr * DIM + lk;
    const float* hpw = hps + wv * 256 + lr;

    half8 bh0, bh1;
    float hpv0, hpv1;
    {
        const int w0 = S;
        const int w1 = (1 + S) & 15;
        bh0 = *(const half8*)(cwb + w0 * (16 * DIM) + laneoff);
        bh1 = *(const half8*)(cwb + w1 * (16 * DIM) + laneoff);
        hpv0 = hpw[w0 * 16];
        hpv1 = hpw[w1 * 16];
    }

    float ms0[4] = {-INFINITY, -INFINITY, -INFINITY, -INFINITY};
    float ms1[4] = {-INFINITY, -INFINITY, -INFINITY, -INFINITY};
    float ss0[4] = {0.f, 0.f, 0.f, 0.f};
    float ss1[4] = {0.f, 0.f, 0.f, 0.f};
    f32x4 ca0[2], ca1[2];

#pragma unroll
    for (int g = 0; g < 8; g++) {
        float hpc0, hpc1;
        {   // ct = 2g
            f32x4 u0 = {0.f, 0.f, 0.f, 0.f};
            f32x4 u1 = {0.f, 0.f, 0.f, 0.f};
            u0 = __builtin_amdgcn_mfma_f32_16x16x32_f16(a0, bh0, u0, 0, 0, 0);
            u1 = __builtin_amdgcn_mfma_f32_16x16x32_f16(a1, bh0, u1, 0, 0, 0);
            hpc0 = hpv0;
            if (g < 7) {
                const int w = ((2 * g + 2) + S) & 15;
                bh0  = *(const half8*)(cwb + w * (16 * DIM) + laneoff);
                hpv0 = hpw[w * 16];
            }
            ca0[0] = u0; ca1[0] = u1;
        }
        {   // ct = 2g+1
            f32x4 u0 = {0.f, 0.f, 0.f, 0.f};
            f32x4 u1 = {0.f, 0.f, 0.f, 0.f};
            u0 = __builtin_amdgcn_mfma_f32_16x16x32_f16(a0, bh1, u0, 0, 0, 0);
            u1 = __builtin_amdgcn_mfma_f32_16x16x32_f16(a1, bh1, u1, 0, 0, 0);
            hpc1 = hpv1;
            if (g < 7) {
                const int w = ((2 * g + 3) + S) & 15;
                bh1  = *(const half8*)(cwb + w * (16 * DIM) + laneoff);
                hpv1 = hpw[w * 16];
            }
            ca0[1] = u0; ca1[1] = u1;
        }
        GLSE2(0, 0) GLSE2(0, 1) GLSE2(0, 2) GLSE2(0, 3)
        GLSE2(1, 0) GLSE2(1, 1) GLSE2(1, 2) GLSE2(1, 3)
    }

    // merge the 16 col-lanes (lane bits 0..3)
#pragma unroll
    for (int wm = 1; wm <= 8; wm <<= 1) {
#pragma unroll
        for (int r = 0; r < 4; r++) {
            float om, os, nm;
            om = __shfl_xor(ms0[r], wm, 64); os = __shfl_xor(ss0[r], wm, 64);
            nm = fmaxf(ms0[r], om);
            ss0[r] = fmaf(ss0[r], exp2fast(ms0[r] - nm), os * exp2fast(om - nm));
            ms0[r] = nm;
            om = __shfl_xor(ms1[r], wm, 64); os = __shfl_xor(ss1[r], wm, 64);
            nm = fmaxf(ms1[r], om);
            ss1[r] = fmaf(ss1[r], exp2fast(ms1[r] - nm), os * exp2fast(om - nm));
            ms1[r] = nm;
        }
    }
    if (lr == 0) {
        const int g4 = (lane >> 4) * 4;
#pragma unroll
        for (int r = 0; r < 4; r++) {
            parts[wv][g4 + r]      = make_float2(ms0[r], ss0[r]);
            parts[wv][16 + g4 + r] = make_float2(ms1[r], ss1[r]);
        }
    }
    __syncthreads();
    if (t < 32) {
        float2 p = parts[0][t];
        float m = p.x, s = p.y;
#pragma unroll
        for (int w2 = 1; w2 < 8; w2++) {
            float2 q = parts[w2][t];
            float nm = fmaxf(m, q.x);
            s = fmaf(s, exp2fast(m - nm), q.y * exp2fast(q.x - nm));
            m = nm;
        }
        const int row = tile * 32 + t;
        float2* Pout = (float2*)(ws + WS_P) + (((slot & 1) * 4 + bm) * 2 + h) * NPTS;
        Pout[row] = make_float2(m, s);     // raw partial (no log here)
    }
}

// ---------------- final: merge last partials -> f; mean(f_ba-f_aa)+mean(g_ab-g_bb)
__global__ void sink_reduce(const float* __restrict__ ws, float* __restrict__ outp)
{
    __shared__ float red[NTHREADS];
    const int* modes = (const int*)(ws + WS_MODE);
    const int niter = modes[62];
    const int last  = niter - 1;
    const float eps_l  = ws[WS_EPS + last];
    const int   mode_l = modes[last];
    const int   pl     = last & 1;
    const float LN2 = 0.6931471805599453f;
    int t = threadIdx.x;
    float acc = 0.f;
    for (int i = t; i < 4 * NPTS; i += NTHREADS) {
        int m = i >> 12, j = i & 4095;
        const float2* P0 = (const float2*)(ws + WS_P) + ((pl * 4 + m) * 2 + 0) * NPTS;
        const float2* P1 = (const float2*)(ws + WS_P) + ((pl * 4 + m) * 2 + 1) * NPTS;
        float2 p0 = P0[j], p1 = P1[j];
        float mm2 = fmaxf(p0.x, p1.x);
        float sv  = p0.y * exp2fast(p0.x - mm2) + p1.y * exp2fast(p1.x - mm2);
        float lse = LN2 * (mm2 + log2fast(sv));
        const float* rn2m = ws + ((m == 0 || m == 2) ? WS_N2X : WS_N2Y);
        float ft = rn2m[j] - eps_l * lse;
        float fv = (mode_l == M_AVG)
                 ? 0.5f * (ws[WS_FBUF + pl * 16384 + m * NPTS + j] + ft) : ft;
        acc += (m <= 1) ? fv : -fv;
    }
    red[t] = acc;
    __syncthreads();
    for (int s = NTHREADS / 2; s > 0; s >>= 1) {
        if (t < s) red[t] += red[t + s];
        __syncthreads();
    }
    if (t == 0) outp[0] = red[0] * (1.0f / (float)NPTS);
}

extern "C" void kernel_launch(void* const* d_in, const int* in_sizes, int n_in,
                              void* d_out, int out_size, void* d_ws, size_t ws_size,
                              hipStream_t stream)
{
    const float* x = (const float*)d_in[0];
    const float* y = (const float*)d_in[1];
    float* ws  = (float*)d_ws;
    float* out = (float*)d_out;

    hipLaunchKernelGGL(sink_setup, dim3(64), dim3(NTHREADS), 0, stream, x, y, ws,
                       (unsigned short*)(ws + WS_BF));
    hipLaunchKernelGGL(sink_sched, dim3(1),  dim3(NTHREADS), 0, stream, ws);
    for (int s = 0; s < MAXSLOTS; s++)
        hipLaunchKernelGGL(sink_iter, dim3(1024), dim3(ITHREADS), 0, stream, ws, s);
    hipLaunchKernelGGL(sink_reduce, dim3(1), dim3(NTHREADS), 0, stream, ws, out);
}

// Round 16
// 882.925 us; speedup vs baseline: 1.3025x; 1.3025x over previous
//
#include <hip/hip_runtime.h>
#include <math.h>

#define NPTS 4096
#define DIM  32
#define MAXSLOTS 50
#define NTHREADS 256
#define ITHREADS 512
#define NELEM 131072      // 4096*32

// ws layout in floats
#define WS_N2X   0
#define WS_N2Y   4096
#define WS_PMIN  8192
#define WS_PMAX  10240
#define WS_EPS   12288
#define WS_MODE  12352    // int modes; [62] = niter
#define WS_DUAL  12416
#define DUALSZ   16384    // 4 arrays * 4096 (one parity buffer)
#define WS_BF    45184    // fp16 pack area: 2*131072 ushorts = 512 KB

// modes
#define M_SKIP   0
#define M_INIT   1
#define M_AVG    2
#define M_ASSIGN 3

typedef short    short8 __attribute__((ext_vector_type(8)));
typedef _Float16 half8  __attribute__((ext_vector_type(8)));
typedef float    f32x4  __attribute__((ext_vector_type(4)));

__device__ __forceinline__ float exp2fast(float a){
#if __has_builtin(__builtin_amdgcn_exp2f)
    return __builtin_amdgcn_exp2f(a);
#else
    return exp2f(a);
#endif
}
__device__ __forceinline__ float log2fast(float a){
#if __has_builtin(__builtin_amdgcn_logf)
    return __builtin_amdgcn_logf(a);
#else
    return log2f(a);
#endif
}

__device__ __forceinline__ short8 pack8(const float* src){
    float4 v0 = ((const float4*)src)[0];
    float4 v1 = ((const float4*)src)[1];
    float vs[8] = {v0.x, v0.y, v0.z, v0.w, v1.x, v1.y, v1.z, v1.w};
    short hv[8];
#pragma unroll
    for (int i = 0; i < 8; i++) {
        union { _Float16 f; short s; } u;
        u.f = (_Float16)vs[i];              // RNE f32->f16
        hv[i] = u.s;
    }
    short8 r = {hv[0],hv[1],hv[2],hv[3],hv[4],hv[5],hv[6],hv[7]};
    return r;
}

// ---------------- fused setup: fp16 pack (x AND y) + norms + minmax partials
__global__ void sink_setup(const float* __restrict__ x, const float* __restrict__ y,
                           float* __restrict__ ws, unsigned short* __restrict__ bf)
{
    __shared__ float2 mm[8][32];
    const int t = threadIdx.x;
    const int b = blockIdx.x;
    const int gtid = b * 256 + t;          // 0..16383

    {
        int e = gtid * 8;
        *(short8*)((short*)bf + e)         = pack8(x + e);
        *(short8*)((short*)bf + NELEM + e) = pack8(y + e);
    }
    if (gtid < 2 * NPTS) {
        const float* src = (gtid < NPTS) ? (x + (size_t)gtid * DIM)
                                         : (y + (size_t)(gtid - NPTS) * DIM);
        const float4* s4 = (const float4*)src;
        float acc = 0.f;
#pragma unroll
        for (int q = 0; q < 8; q++) {
            float4 v = s4[q];
            acc += v.x*v.x + v.y*v.y + v.z*v.z + v.w*v.w;
        }
        ws[gtid] = 0.5f * acc;
    }
    {
        int d = t & 31, rg = t >> 5;
        float mn = 3.4e38f, mx = -3.4e38f;
#pragma unroll
        for (int k = 0; k < 16; k++) {
            int row = b * 128 + k * 8 + rg;
            const float* src = (row < NPTS) ? (x + (size_t)row * DIM)
                                            : (y + (size_t)(row - NPTS) * DIM);
            float v = src[d];
            mn = fminf(mn, v); mx = fmaxf(mx, v);
        }
        mm[rg][d] = make_float2(mn, mx);
    }
    __syncthreads();
    if (t < 32) {
        float2 a = mm[0][t];
#pragma unroll
        for (int g = 1; g < 8; g++) {
            float2 p = mm[g][t];
            a.x = fminf(a.x, p.x); a.y = fmaxf(a.y, p.y);
        }
        ws[WS_PMIN + b * 32 + t] = a.x;
        ws[WS_PMAX + b * 32 + t] = a.y;
    }
}

// ---------------- schedule: diameter -> eps list + mode per slot (+niter)
__global__ void sink_sched(float* __restrict__ ws)
{
    __shared__ float mins[32], maxs[32];
    int t = threadIdx.x;
    if (t < 32) {
        float mn = 3.4e38f, mx = -3.4e38f;
        for (int b = 0; b < 64; b++) {
            mn = fminf(mn, ws[WS_PMIN + b * 32 + t]);
            mx = fmaxf(mx, ws[WS_PMAX + b * 32 + t]);
        }
        mins[t] = mn; maxs[t] = mx;
    }
    __syncthreads();
    if (t == 0) {
        float dia2 = 0.f;
        for (int d = 0; d < 32; d++) {
            float df = maxs[d] - mins[d];
            dia2 += df * df;
        }
        float dia = sqrtf(dia2);
        float* eps = ws + WS_EPS;
        int*  mode = (int*)(ws + WS_MODE);
        double ld    = log((double)dia);
        double start = 2.0 * ld;
        double stop  = 2.0 * log(0.5);
        double step  = 2.0 * log(0.9);
        int K = (int)ceil((stop - start) / step);
        if (K < 0) K = 0;
        if (K > MAXSLOTS - 4) K = MAXSLOTS - 4;
        eps[0] = dia * dia; mode[0] = M_INIT;
        eps[1] = dia * dia; mode[1] = M_AVG;
        for (int k = 0; k < K; k++) {
            eps[2 + k] = (float)exp(start + step * (double)k);
            mode[2 + k] = M_AVG;
        }
        eps[2 + K] = 0.25f; mode[2 + K] = M_AVG;
        eps[3 + K] = 0.25f; mode[3 + K] = M_ASSIGN;
        for (int s = 4 + K; s < MAXSLOTS; s++) { eps[s] = 0.25f; mode[s] = M_SKIP; }
        mode[62] = K + 4;                   // niter (parity for the reducer)
    }
}

// grouped online-LSE over 4 accumulated cts, for tile T register R
#define GLSE(T, R) \
    { float v0 = fmaf(ca##T[0][R], ie2, hpr[0]); \
      float v1 = fmaf(ca##T[1][R], ie2, hpr[1]); \
      float v2 = fmaf(ca##T[2][R], ie2, hpr[2]); \
      float v3 = fmaf(ca##T[3][R], ie2, hpr[3]); \
      float gm = fmaxf(fmaxf(v0, v1), v2); \
      float nm = fmaxf(fmaxf(gm, v3), ms##T[R]); \
      float er = exp2fast(ms##T[R] - nm); \
      float e0 = exp2fast(v0 - nm); \
      float e1 = exp2fast(v1 - nm); \
      float e2 = exp2fast(v2 - nm); \
      float e3 = exp2fast(v3 - nm); \
      ss##T[R] = fmaf(ss##T[R], er, (e0 + e1) + (e2 + e3)); \
      ms##T[R] = nm; }

// ---------------- fused softmin iteration (R8 body: best measured, 888 us total)
// grid = 4 matrices * 128 row-tiles(32 rows) = 512 blocks, 512 threads (8 waves)
// block: 32 rows (2 MFMA row-tiles per wave); wave w: cols [w*512,(w+1)*512)
// column sweep skewed per block to de-phase the shared B stream in L2
__global__ __launch_bounds__(ITHREADS, 4) void sink_iter(float* __restrict__ ws, int slot)
{
    const int t = threadIdx.x;
    const int mode = ((const int*)(ws + WS_MODE))[slot];
    if (mode == M_SKIP) return;            // true no-op: reducer reads parity

    const float eps     = ws[WS_EPS + slot];
    const float inv_eps = 1.0f / eps;
    const float L2E     = 1.4426950408889634f;
    const float LN2     = 0.6931471805599453f;
    const float ie2     = inv_eps * L2E;
    const float hbase   = -8.317766166719343f;   // -ln(4096)
    const float don     = (mode == M_INIT) ? 0.0f : 1.0f;

    const int bm   = blockIdx.x >> 7;     // 0=xy 1=yx 2=xx 3=yy
    const int tile = blockIdx.x & 127;
    const int S    = (blockIdx.x * 5) & 31;   // per-block sweep skew
    const int rowIsX = (bm == 0 || bm == 2);
    const int colIsX = (bm == 1 || bm == 2);

    const short* bf = (const short*)(ws + WS_BF);
    const short* rbase = bf + (rowIsX ? 0 : NELEM);
    const short* cbase = bf + (colIsX ? 0 : NELEM);
    const float* rn2 = ws + (rowIsX ? WS_N2X : WS_N2Y);
    const float* cn2 = ws + (colIsX ? WS_N2X : WS_N2Y);

    const float* bufold = ws + WS_DUAL + (slot & 1) * DUALSZ;
    float*       bufnew = ws + WS_DUAL + ((slot + 1) & 1) * DUALSZ;
    const int dualsel = (bm == 0) ? 1 : (bm == 1) ? 0 : bm;   // {1,0,2,3}
    const float* dual   = bufold + dualsel * NPTS;
    const float* oldout = bufold + bm * NPTS;
    float*       out    = bufnew + bm * NPTS;

    __shared__ float  hps[NPTS];          // 16 KB
    __shared__ float2 parts[8][32];       // 2 KB

    const int lane = t & 63;
    const int wv   = t >> 6;
    const int lr   = lane & 15;
    const int lk   = (lane >> 4) * 8;

    // A fragments: two row-tiles (rows tile*32+lr and tile*32+16+lr)
    const int ar0 = tile * 32 + lr;
    const half8 a0 = *(const half8*)(rbase + ar0 * DIM + lk);
    const half8 a1 = *(const half8*)(rbase + (ar0 + 16) * DIM + lk);

    // build hp[j] for all 4096 cols (coalesced)
#pragma unroll
    for (int q = 0; q < 8; q++) {
        int j = t + q * ITHREADS;
        hps[j] = (hbase + fmaf(don, dual[j], -cn2[j]) * inv_eps) * L2E;
    }
    __syncthreads();

    // wave's column window; depth-6 ring for B fragments and hp
    const int colbase = wv * 512;
    const short* cwb = cbase + (size_t)colbase * DIM;
    const int laneoff = lr * DIM + lk;
    const float* hpw = hps + colbase + lr;

    half8 bh[6];
    float hpv[6];
#pragma unroll
    for (int p = 0; p < 6; p++) {
        const int w = (p + S) & 31;
        bh[p]  = *(const half8*)(cwb + w * (16 * DIM) + laneoff);
        hpv[p] = hpw[w * 16];
    }

    float ms0[4] = {-INFINITY, -INFINITY, -INFINITY, -INFINITY};
    float ms1[4] = {-INFINITY, -INFINITY, -INFINITY, -INFINITY};
    float ss0[4] = {0.f, 0.f, 0.f, 0.f};
    float ss1[4] = {0.f, 0.f, 0.f, 0.f};

    f32x4 ca0[4], ca1[4];
    float hpr[4];

#pragma unroll
    for (int ct = 0; ct < 32; ct++) {
        const int sl = ct % 6;            // ring slot (compile-time in unrolled loop)
        const half8 hB = bh[sl];
        hpr[ct & 3] = hpv[sl];
        f32x4 u0 = {0.f, 0.f, 0.f, 0.f};
        f32x4 u1 = {0.f, 0.f, 0.f, 0.f};
        u0 = __builtin_amdgcn_mfma_f32_16x16x32_f16(a0, hB, u0, 0, 0, 0);
        u1 = __builtin_amdgcn_mfma_f32_16x16x32_f16(a1, hB, u1, 0, 0, 0);
        if (ct < 26) {
            const int w = ((ct + 6) + S) & 31;
            bh[sl]  = *(const half8*)(cwb + w * (16 * DIM) + laneoff);
            hpv[sl] = hpw[w * 16];
        }
        ca0[ct & 3] = u0;
        ca1[ct & 3] = u1;
        if ((ct & 3) == 3) {
            GLSE(0, 0) GLSE(0, 1) GLSE(0, 2) GLSE(0, 3)
            GLSE(1, 0) GLSE(1, 1) GLSE(1, 2) GLSE(1, 3)
        }
    }

    // merge the 16 col-lanes (lane bits 0..3)
#pragma unroll
    for (int wm = 1; wm <= 8; wm <<= 1) {
#pragma unroll
        for (int r = 0; r < 4; r++) {
            float om, os, nm;
            om = __shfl_xor(ms0[r], wm, 64); os = __shfl_xor(ss0[r], wm, 64);
            nm = fmaxf(ms0[r], om);
            ss0[r] = fmaf(ss0[r], exp2fast(ms0[r] - nm), os * exp2fast(om - nm));
            ms0[r] = nm;
            om = __shfl_xor(ms1[r], wm, 64); os = __shfl_xor(ss1[r], wm, 64);
            nm = fmaxf(ms1[r], om);
            ss1[r] = fmaf(ss1[r], exp2fast(ms1[r] - nm), os * exp2fast(om - nm));
            ms1[r] = nm;
        }
    }
    if (lr == 0) {
        const int g4 = (lane >> 4) * 4;
#pragma unroll
        for (int r = 0; r < 4; r++) {
            parts[wv][g4 + r]      = make_float2(ms0[r], ss0[r]);
            parts[wv][16 + g4 + r] = make_float2(ms1[r], ss1[r]);
        }
    }
    __syncthreads();
    if (t < 32) {
        float2 p = parts[0][t];
        float m = p.x, s = p.y;
#pragma unroll
        for (int w2 = 1; w2 < 8; w2++) {
            float2 q = parts[w2][t];
            float nm = fmaxf(m, q.x);
            s = fmaf(s, exp2fast(m - nm), q.y * exp2fast(q.x - nm));
            m = nm;
        }
        const float lse = LN2 * (m + log2fast(s));
        const int row = tile * 32 + t;
        const float ft = rn2[row] - eps * lse;
        out[row] = (mode == M_AVG) ? 0.5f * (oldout[row] + ft) : ft;
    }
}

// ---------------- final: mean(f_ba - f_aa) + mean(g_ab - g_bb), parity-aware
__global__ void sink_reduce(const float* __restrict__ ws, float* __restrict__ outp)
{
    __shared__ float red[NTHREADS];
    const int niter = ((const int*)(ws + WS_MODE))[62];
    const float* b = ws + WS_DUAL + (niter & 1) * DUALSZ;
    int t = threadIdx.x;
    float acc = 0.f;
    for (int i = t; i < NPTS; i += NTHREADS)
        acc += (b[i] - b[2 * NPTS + i]) + (b[NPTS + i] - b[3 * NPTS + i]);
    red[t] = acc;
    __syncthreads();
    for (int s = NTHREADS / 2; s > 0; s >>= 1) {
        if (t < s) red[t] += red[t + s];
        __syncthreads();
    }
    if (t == 0) outp[0] = red[0] * (1.0f / (float)NPTS);
}

extern "C" void kernel_launch(void* const* d_in, const int* in_sizes, int n_in,
                              void* d_out, int out_size, void* d_ws, size_t ws_size,
                              hipStream_t stream)
{
    const float* x = (const float*)d_in[0];
    const float* y = (const float*)d_in[1];
    float* ws  = (float*)d_ws;
    float* out = (float*)d_out;

    hipLaunchKernelGGL(sink_setup, dim3(64), dim3(NTHREADS), 0, stream, x, y, ws,
                       (unsigned short*)(ws + WS_BF));
    hipLaunchKernelGGL(sink_sched, dim3(1),  dim3(NTHREADS), 0, stream, ws);
    for (int s = 0; s < MAXSLOTS; s++)
        hipLaunchKernelGGL(sink_iter, dim3(512), dim3(ITHREADS), 0, stream, ws, s);
    hipLaunchKernelGGL(sink_reduce, dim3(1), dim3(NTHREADS), 0, stream, ws, out);
}